// Round 1
// baseline (273.575 us; speedup 1.0000x reference)
//
#include <hip/hip_runtime.h>

// MN neuron forward sim: T=1000 sequential steps, 64x512 independent chains.
// Round 3 structure: NO barriers, NO LDS, NO producer wave.
//   Each lane owns one chain; x loaded directly with a K_CHUNK-deep register
//   prefetch ring (coalesced 256B/wave). Stores are fire-and-forget
//   nontemporal; vmcnt is never force-drained by __syncthreads (the round-2
//   kernel drained 20 outstanding HBM stores at every chunk barrier).
// CORRECTNESS: binary spike output => bit-exact f32 vs numpy ref:
//   exact reference op order, no FMA contraction, selects for spike resets.
//   mn_step is byte-identical to the verified round-2 version.

#define T_STEPS 1000
#define B_DIM 64
#define N_DIM 512
#define BN (B_DIM * N_DIM)   // 32768

#define K_CHUNK 20
#define NCHUNK (T_STEPS / K_CHUNK)   // 50

// f32-rounded constants
#define C_DT   0.01f
#define C_EL   (-0.07f)
#define C_VR   (-0.07f)
#define C_TR   (-0.06f)
#define C_TINF (-0.05f)
#define C_B    12.77495288848877f
#define C_G    45.24007797241211f
#define C_K1   200.0f
#define C_K2   20.0f
#define C_R1   0.3858567178249359f
#define C_R2   (-1.1421641111373901f)

__device__ __forceinline__ float mn_step(float xt, float lin, float av,
                                         float A1v, float A2v,
                                         float& V, float& i1, float& i2,
                                         float& Thr)
{
#pragma clang fp contract(off)
    i1 = i1 - (C_K1 * i1) * C_DT;
    i2 = i2 - (C_K2 * i2) * C_DT;
    float p  = lin * xt;
    float q  = p + i1;
    float r  = q + i2;
    float e  = V - C_EL;
    float g  = C_G * e;
    float s  = r - g;
    float d  = C_DT * s;
    V = V + d;
    float e2 = V - C_EL;
    float u  = av * e2;
    float w  = Thr - C_TINF;
    float bw = C_B * w;
    float s2 = u - bw;
    float d2 = C_DT * s2;
    Thr = Thr + d2;
    float diff = V - Thr;
    bool  sb   = diff > 0.0f;
    float spk  = sb ? 1.0f : 0.0f;
    float i1r = (C_R1 * i1) + A1v;
    float i2r = (C_R2 * i2) + A2v;
    i1  = sb ? i1r : i1;
    i2  = sb ? i2r : i2;
    float tm = fmaxf(Thr, C_TR);
    Thr = sb ? tm : Thr;
    V   = sb ? C_VR : V;
    return spk;
}

__global__ __launch_bounds__(64) void mn_neuron_kernel(
    const float* __restrict__ x, const float* __restrict__ linear,
    const float* __restrict__ a, const float* __restrict__ A1,
    const float* __restrict__ A2, float* __restrict__ out)
{
#pragma clang fp contract(off)
    const int lane = threadIdx.x;                 // 0..63
    const int idx  = blockIdx.x * 64 + lane;      // b*N + n
    const int n    = idx & (N_DIM - 1);

    const float lin = linear[n];
    const float av  = a[n];
    const float A1v = A1[n];
    const float A2v = A2[n];

    float V   = C_EL;
    float i1  = 0.0f;
    float i2  = 0.0f;
    float Thr = C_TINF;

    const float* xp = x + idx;    // chunk-c base advances by K_CHUNK*BN
    float*       op = out + idx;

    // K_CHUNK-deep register prefetch ring. All indices compile-time constant
    // in the unrolled loops -> stays in VGPRs (no scratch).
    float xb[K_CHUNK];

    // prologue: chunk 0 in flight
#pragma unroll
    for (int j = 0; j < K_CHUNK; ++j)
        xb[j] = xp[(size_t)j * BN];
    xp += (size_t)K_CHUNK * BN;

    for (int c = 0; c < NCHUNK - 1; ++c) {
#pragma unroll
        for (int j = 0; j < K_CHUNK; ++j) {
            float xt = xb[j];
            // prefetch same slot for chunk c+1; issued now, used one full
            // chunk (~20 * ~100 cyc) later -> HBM latency fully covered.
            xb[j] = xp[(size_t)j * BN];
            float spk = mn_step(xt, lin, av, A1v, A2v, V, i1, i2, Thr);
            __builtin_nontemporal_store(spk, op);
            op += BN;
        }
        xp += (size_t)K_CHUNK * BN;
    }

    // epilogue chunk: no prefetch
#pragma unroll
    for (int j = 0; j < K_CHUNK; ++j) {
        float xt  = xb[j];
        float spk = mn_step(xt, lin, av, A1v, A2v, V, i1, i2, Thr);
        __builtin_nontemporal_store(spk, op);
        op += BN;
    }
}

extern "C" void kernel_launch(void* const* d_in, const int* in_sizes, int n_in,
                              void* d_out, int out_size, void* d_ws, size_t ws_size,
                              hipStream_t stream) {
    const float* x      = (const float*)d_in[0];
    const float* linear = (const float*)d_in[1];
    const float* a      = (const float*)d_in[2];
    const float* A1     = (const float*)d_in[3];
    const float* A2     = (const float*)d_in[4];
    float* out = (float*)d_out;

    // 512 blocks x 64 threads: one wave per block, one chain per lane.
    mn_neuron_kernel<<<BN / 64, 64, 0, stream>>>(x, linear, a, A1, A2, out);
}

// Round 2
// 234.416 us; speedup vs baseline: 1.1670x; 1.1670x over previous
//
#include <hip/hip_runtime.h>

// MN neuron forward sim: T=1000 sequential steps, 64x512 independent chains.
// Round 4 structure: round-2 producer/consumer (proven 80us) minus its stalls.
//   wave 1 (producer): global -> LDS double-buffer via global_load_lds w=16,
//                      explicit s_waitcnt vmcnt(0) (per-wave counter: loads only)
//   wave 0 (consumer): RAW s_barrier (no vmcnt drain -> 20 outstanding HBM
//                      stores per chunk are never waited on), chunk's 20 x
//                      values batch-read into registers (one LDS latency per
//                      chunk instead of per step), nontemporal stores.
// Round-3 lesson (VGPR=28): compiler sinks plain global loads, collapsing
// register prefetch rings. global_load_lds has no register result -> the
// producer's flight depth cannot be collapsed.
// CORRECTNESS: binary spike output => bit-exact f32 vs numpy ref:
//   exact reference op order, no FMA contraction, selects for spike resets.
//   mn_step is byte-identical to the verified round-2 version.
//   Barrier count: producer 1+50, consumer 1+50 (both waves arrive). Double
//   buffer: producer fills buf[(c+1)&1] during consumer's chunk c on buf[c&1];
//   buf[c&1] is only overwritten after barrier #c+1, by which point the
//   consumer has consumed all its ds_read values (register data dependence).

#define T_STEPS 1000
#define B_DIM 64
#define N_DIM 512
#define BN (B_DIM * N_DIM)   // 32768

#define K_CHUNK 20
#define NCHUNK (T_STEPS / K_CHUNK)   // 50

// f32-rounded constants
#define C_DT   0.01f
#define C_EL   (-0.07f)
#define C_VR   (-0.07f)
#define C_TR   (-0.06f)
#define C_TINF (-0.05f)
#define C_B    12.77495288848877f
#define C_G    45.24007797241211f
#define C_K1   200.0f
#define C_K2   20.0f
#define C_R1   0.3858567178249359f
#define C_R2   (-1.1421641111373901f)

typedef const __attribute__((address_space(1))) void* gp_t;
typedef __attribute__((address_space(3))) void* lp_t;

__device__ __forceinline__ void raw_barrier() {
    // s_barrier WITHOUT the compiler's vmcnt(0)/lgkmcnt(0) drain that
    // __syncthreads() emits. "memory" clobber = compiler ordering fence only.
    asm volatile("s_barrier" ::: "memory");
}

__device__ __forceinline__ float mn_step(float xt, float lin, float av,
                                         float A1v, float A2v,
                                         float& V, float& i1, float& i2,
                                         float& Thr)
{
#pragma clang fp contract(off)
    i1 = i1 - (C_K1 * i1) * C_DT;
    i2 = i2 - (C_K2 * i2) * C_DT;
    float p  = lin * xt;
    float q  = p + i1;
    float r  = q + i2;
    float e  = V - C_EL;
    float g  = C_G * e;
    float s  = r - g;
    float d  = C_DT * s;
    V = V + d;
    float e2 = V - C_EL;
    float u  = av * e2;
    float w  = Thr - C_TINF;
    float bw = C_B * w;
    float s2 = u - bw;
    float d2 = C_DT * s2;
    Thr = Thr + d2;
    float diff = V - Thr;
    bool  sb   = diff > 0.0f;
    float spk  = sb ? 1.0f : 0.0f;
    float i1r = (C_R1 * i1) + A1v;
    float i2r = (C_R2 * i2) + A2v;
    i1  = sb ? i1r : i1;
    i2  = sb ? i2r : i2;
    float tm = fmaxf(Thr, C_TR);
    Thr = sb ? tm : Thr;
    V   = sb ? C_VR : V;
    return spk;
}

__global__ __launch_bounds__(128) void mn_neuron_kernel(
    const float* __restrict__ x, const float* __restrict__ linear,
    const float* __restrict__ a, const float* __restrict__ A1,
    const float* __restrict__ A2, float* __restrict__ out)
{
#pragma clang fp contract(off)
    // lds[buf][t_in_chunk][lane]
    __shared__ float lds[2][K_CHUNK][64];

    const int lane = threadIdx.x & 63;
    const int wid  = threadIdx.x >> 6;     // 0 = consumer, 1 = producer
    const int blk  = blockIdx.x;

    if (wid == 1) {
        // ---- producer ----
        // width-16 global_load_lds: lane l loads 16B covering
        // row (l>>4) of the 4-row group, floats (l&15)*4 .. +3.
        // LDS dest = uniform base + l*16  ->  lds[buf][s*4 + (l>>4)][(l&15)*4..]
        const float* pl = x + (size_t)(lane >> 4) * BN
                            + (size_t)blk * 64 + (size_t)(lane & 15) * 4;

        // prologue: chunk 0 -> buf 0
        {
#pragma unroll
            for (int s = 0; s < K_CHUNK / 4; ++s) {
                __builtin_amdgcn_global_load_lds(
                    (gp_t)(pl + (size_t)(s * 4) * BN),
                    (lp_t)&lds[0][s * 4][0], 16, 0, 0);
            }
            asm volatile("s_waitcnt vmcnt(0)" ::: "memory");
        }
        raw_barrier();

        for (int c = 0; c < NCHUNK; ++c) {
            if (c + 1 < NCHUNK) {
                const float* pc = pl + (size_t)((c + 1) * K_CHUNK) * BN;
                float* dst = &lds[(c + 1) & 1][0][0];
#pragma unroll
                for (int s = 0; s < K_CHUNK / 4; ++s) {
                    __builtin_amdgcn_global_load_lds(
                        (gp_t)(pc + (size_t)(s * 4) * BN),
                        (lp_t)(dst + s * 4 * 64), 16, 0, 0);
                }
                asm volatile("s_waitcnt vmcnt(0)" ::: "memory");
            }
            raw_barrier();
        }
    } else {
        // ---- consumer ----
        const int idx = blk * 64 + lane;       // b*N + n
        const int n   = idx & (N_DIM - 1);

        const float lin = linear[n];
        const float av  = a[n];
        const float A1v = A1[n];
        const float A2v = A2[n];

        float V   = C_EL;
        float i1  = 0.0f;
        float i2  = 0.0f;
        float Thr = C_TINF;

        float* op = out + idx;

        raw_barrier();   // matches producer prologue barrier: buf0 ready

        for (int c = 0; c < NCHUNK; ++c) {
            const float* src = &lds[c & 1][0][lane];

            // Batch the chunk's LDS reads: 20 ds_read_b32 issued back-to-back
            // (imm offsets j*256, 2-way bank alias = free). One pipelined LDS
            // latency per chunk; compiler emits fine-grained lgkmcnt(N) waits.
            float xv[K_CHUNK];
#pragma unroll
            for (int j = 0; j < K_CHUNK; ++j)
                xv[j] = src[j * 64];

#pragma unroll
            for (int j = 0; j < K_CHUNK; ++j) {
                float spk = mn_step(xv[j], lin, av, A1v, A2v, V, i1, i2, Thr);
                __builtin_nontemporal_store(spk, op);
                op += BN;
            }
            raw_barrier();   // fire-and-forget stores: NO vmcnt drain here
        }
    }
}

extern "C" void kernel_launch(void* const* d_in, const int* in_sizes, int n_in,
                              void* d_out, int out_size, void* d_ws, size_t ws_size,
                              hipStream_t stream) {
    const float* x      = (const float*)d_in[0];
    const float* linear = (const float*)d_in[1];
    const float* a      = (const float*)d_in[2];
    const float* A1     = (const float*)d_in[3];
    const float* A2     = (const float*)d_in[4];
    float* out = (float*)d_out;

    // 512 blocks x 128 threads (1 consumer wave + 1 producer wave each)
    mn_neuron_kernel<<<BN / 64, 128, 0, stream>>>(x, linear, a, A1, A2, out);
}